// Round 12
// baseline (253.393 us; speedup 1.0000x reference)
//
#include <hip/hip_runtime.h>

#define N_NODES 50000
#define N_EDGES 800000

static inline size_t align256(size_t x) { return (x + 255) & ~(size_t)255; }

typedef _Float16 f16x8 __attribute__((ext_vector_type(8)));   // 8 fp16 in 4 VGPRs
typedef float f32x4 __attribute__((ext_vector_type(4)));
typedef float f32x8 __attribute__((ext_vector_type(8)));

// ---------------- CSR build ----------------

__global__ void count_kernel(const int* __restrict__ dst, int* __restrict__ counts,
                             int* __restrict__ rank, int E) {
    int e = blockIdx.x * blockDim.x + threadIdx.x;
    if (e < E) rank[e] = atomicAdd(&counts[dst[e]], 1);
}

__global__ void scan1_kernel(const int* __restrict__ counts, int* __restrict__ row_ptr,
                             int* __restrict__ bsum, int n) {
    __shared__ int sd[1024];
    int i = blockIdx.x * 1024 + threadIdx.x;
    int v = (i < n) ? counts[i] : 0;
    sd[threadIdx.x] = v;
    __syncthreads();
    #pragma unroll
    for (int off = 1; off < 1024; off <<= 1) {
        int t = 0;
        if ((int)threadIdx.x >= off) t = sd[threadIdx.x - off];
        __syncthreads();
        sd[threadIdx.x] += t;
        __syncthreads();
    }
    if (i < n) row_ptr[i + 1] = sd[threadIdx.x];
    if (threadIdx.x == 1023) bsum[blockIdx.x] = sd[1023];
}

// finalize scan (local sum over <=48 block sums), plus dis.
__global__ void scan3_kernel(int* __restrict__ row_ptr, const int* __restrict__ bsum,
                             const int* __restrict__ counts, float* __restrict__ dis, int n) {
    __shared__ int pfx_s;
    if (threadIdx.x == 0) {
        int nb = blockIdx.x >> 2;        // 1024/256
        int p = 0;
        for (int j = 0; j < nb; ++j) p += bsum[j];
        pfx_s = p;
    }
    __syncthreads();
    int i = blockIdx.x * blockDim.x + threadIdx.x;
    if (i < n) {
        row_ptr[i + 1] += pfx_s;
        dis[i] = rsqrtf((float)(counts[i] + 1));
        if (i == 0) row_ptr[0] = 0;
    }
}

__global__ void fill_kernel(const int* __restrict__ src, const int* __restrict__ dst,
                            const int* __restrict__ rank, const int* __restrict__ row_ptr,
                            int* __restrict__ col, int E) {
    int e = blockIdx.x * blockDim.x + threadIdx.x;
    if (e < E) col[row_ptr[dst[e]] + rank[e]] = src[e];
}

// ---------------- fused prep: pack 4 weights (hi/lo frag order) + xs (chunked) ----------

__device__ __forceinline__ void pack_dev(const float* __restrict__ W,
                                         _Float16* __restrict__ Ph, _Float16* __restrict__ Pl,
                                         int K, int N, int id) {
    int l = id & 63;
    int f = id >> 6;
    int nf16 = N >> 4;
    int ks = f / nf16, nf = f - ks * nf16;
    int k0 = ks * 32 + (l >> 4) * 8;
    int n  = nf * 16 + (l & 15);
    #pragma unroll
    for (int j = 0; j < 8; ++j) {
        float v = W[(size_t)(k0 + j) * N + n];
        _Float16 hi = (_Float16)v;
        Ph[(size_t)id * 8 + j] = hi;
        Pl[(size_t)id * 8 + j] = (_Float16)(v - (float)hi);
    }
}

__global__ void prep_kernel(const float* __restrict__ W1, _Float16* __restrict__ w1h, _Float16* __restrict__ w1l,
                            const float* __restrict__ W2, _Float16* __restrict__ w2h, _Float16* __restrict__ w2l,
                            const float* __restrict__ W3, _Float16* __restrict__ w3h, _Float16* __restrict__ w3l,
                            const float* __restrict__ W4, _Float16* __restrict__ w4h, _Float16* __restrict__ w4l,
                            const float* __restrict__ x, const float* __restrict__ dis,
                            _Float16* __restrict__ xs) {
    int b = blockIdx.x;
    int tid = threadIdx.x;
    if (b < 16) {                       // W1: 4096 ids
        pack_dev(W1, w1h, w1l, 128, 256, b * 256 + tid);
    } else if (b < 24) {                // W2: 2048 ids
        pack_dev(W2, w2h, w2l, 256, 64, (b - 16) * 256 + tid);
    } else if (b < 32) {                // W3: 2048 ids
        pack_dev(W3, w3h, w3l, 64, 256, (b - 24) * 256 + tid);
    } else if (b < 48) {                // W4: 4096 ids
        pack_dev(W4, w4h, w4l, 256, 128, (b - 32) * 256 + tid);
    } else {                            // xs: N*16 octs, written CHUNKED [4][N][4 octs]
        int q = (b - 48) * 256 + tid;
        if (q < N_NODES * 16) {
            int v = q >> 4, o = q & 15;
            float s = dis[v];
            const float* px = x + (size_t)v * 128 + o * 8;
            float4 t0 = *(const float4*)px;
            float4 t1 = *(const float4*)(px + 4);
            f16x8 h;
            h[0] = (_Float16)(s * t0.x); h[1] = (_Float16)(s * t0.y);
            h[2] = (_Float16)(s * t0.z); h[3] = (_Float16)(s * t0.w);
            h[4] = (_Float16)(s * t1.x); h[5] = (_Float16)(s * t1.y);
            h[6] = (_Float16)(s * t1.z); h[7] = (_Float16)(s * t1.w);
            ((f16x8*)xs)[(size_t)(o >> 2) * (N_NODES * 4) + (size_t)v * 4 + (o & 3)] = h;
        }
    }
}

// ---------------- Fused GEMM1+GEMM2 (fp16 split x3), NO gather ----------------
// Same as round 11 except the epilogue writes G16 in CHUNKED layout [N2/32][M][32].

template <int K1, int N2>
__global__ __launch_bounds__(256) void fused_gemm(
    const _Float16* __restrict__ Ah, const _Float16* __restrict__ Al,
    const float* __restrict__ dis, const float* __restrict__ bias1,
    const _Float16* __restrict__ B1h, const _Float16* __restrict__ B1l,
    const _Float16* __restrict__ B2h, const _Float16* __restrict__ B2l,
    _Float16* __restrict__ G16, int M) {

    constexpr int KS  = K1 / 32;    // GEMM1 k-slices (= A1 frag count)
    constexpr int NF2 = N2 / 16;
    constexpr int NT2 = N2 / 64;
    constexpr int CS  = 16 / NF2;   // slices per B2 chunk (chunk = 1024 octs per h/l)
    constexpr int KT2 = 8 / CS;     // B2 chunks

    __shared__ __align__(16) char ldsb[69632];
    f16x8* stg = (f16x8*)ldsb;      // [buf][hi/lo][1024]

    const int t = threadIdx.x, w = t >> 6, l = t & 63;
    const int lrow = l & 15, lh = l >> 4;
    const int m0 = blockIdx.x * 64 + w * 16;
    const int v = m0 + lrow;
    const bool okv = v < M;

    // ---- A1 frags from global (hi/lo already split) ----
    f16x8 z8 = {0, 0, 0, 0, 0, 0, 0, 0};
    const f16x8* pAh = (const f16x8*)(Ah + (size_t)v * K1);
    const f16x8* pAl = (const f16x8*)(Al + (size_t)v * K1);
    f16x8 pah[KS], pal[KS];
    #pragma unroll
    for (int ks = 0; ks < KS; ++ks) {
        pah[ks] = okv ? pAh[ks * 4 + lh] : z8;
        pal[ks] = okv ? pAl[ks * 4 + lh] : z8;
    }

    // ---- phase B: GEMM1 (N1 = 256, 16 frags per slice), LDS-dbuf ----
    const f16x8* b1h8 = (const f16x8*)B1h;
    const f16x8* b1l8 = (const f16x8*)B1l;
    f16x8 ph[4], pl[4];
    #pragma unroll
    for (int j = 0; j < 4; ++j) { ph[j] = b1h8[j * 256 + t]; pl[j] = b1l8[j * 256 + t]; }

    f32x4 acc1[4][4] = {};
    #pragma unroll
    for (int ks = 0; ks < KS; ++ks) {
        const int cur = ks & 1;
        #pragma unroll
        for (int j = 0; j < 4; ++j) {
            stg[(cur * 2 + 0) * 1024 + j * 256 + t] = ph[j];
            stg[(cur * 2 + 1) * 1024 + j * 256 + t] = pl[j];
        }
        if (ks + 1 < KS) {
            #pragma unroll
            for (int j = 0; j < 4; ++j) {
                ph[j] = b1h8[(size_t)(ks + 1) * 1024 + j * 256 + t];
                pl[j] = b1l8[(size_t)(ks + 1) * 1024 + j * 256 + t];
            }
        }
        __syncthreads();
        const f16x8* lbh = stg + (cur * 2 + 0) * 1024;
        const f16x8* lbl = stg + (cur * 2 + 1) * 1024;
        #pragma unroll
        for (int nt = 0; nt < 4; ++nt)
            #pragma unroll
            for (int c = 0; c < 4; ++c) {
                f16x8 bh = lbh[(nt * 4 + c) * 64 + l];
                f16x8 bl = lbl[(nt * 4 + c) * 64 + l];
                acc1[nt][c] = __builtin_amdgcn_mfma_f32_16x16x32_f16(pah[ks], bh, acc1[nt][c], 0, 0, 0);
                acc1[nt][c] = __builtin_amdgcn_mfma_f32_16x16x32_f16(pal[ks], bh, acc1[nt][c], 0, 0, 0);
                acc1[nt][c] = __builtin_amdgcn_mfma_f32_16x16x32_f16(pah[ks], bl, acc1[nt][c], 0, 0, 0);
            }
        __syncthreads();
    }

    // ---- phase C: h = relu(acc1 + b1) -> per-wave LDS transpose ----
    float* xp = (float*)ldsb + (size_t)w * 4352;   // [col 0..255][row 0..15], stride 17
    #pragma unroll
    for (int nt = 0; nt < 4; ++nt)
        #pragma unroll
        for (int c = 0; c < 4; ++c) {
            float bb = bias1[nt * 64 + c * 16 + lrow];
            #pragma unroll
            for (int r = 0; r < 4; ++r) {
                float hv = fmaxf(acc1[nt][c][r] + bb, 0.f);
                xp[(nt * 64 + c * 16 + lrow) * 17 + lh * 4 + r] = hv;
            }
        }

    // prefetch B2 chunk 0 into regs (global latency overlaps phase D LDS reads)
    const f16x8* b2h8 = (const f16x8*)B2h;
    const f16x8* b2l8 = (const f16x8*)B2l;
    #pragma unroll
    for (int j = 0; j < 4; ++j) { ph[j] = b2h8[j * 256 + t]; pl[j] = b2l8[j * 256 + t]; }

    // ---- phase D: A2 frags from transpose (row = lrow, k = lh*8 + j + 32*ks2) ----
    f16x8 a2h[8], a2l[8];
    #pragma unroll
    for (int ks2 = 0; ks2 < 8; ++ks2)
        #pragma unroll
        for (int j = 0; j < 8; ++j) {
            float vv = xp[(ks2 * 32 + lh * 8 + j) * 17 + lrow];
            a2h[ks2][j] = (_Float16)vv;
            a2l[ks2][j] = (_Float16)(vv - (float)a2h[ks2][j]);
        }
    __syncthreads();                 // all xpose reads done before B2 staging

    // ---- phase E: GEMM2 (K2 = 256 = 8 slices, staged in chunks of CS slices) ----
    f32x4 acc2[NT2][4] = {};
    #pragma unroll
    for (int kc = 0; kc < KT2; ++kc) {
        const int cur = kc & 1;
        #pragma unroll
        for (int j = 0; j < 4; ++j) {
            stg[(cur * 2 + 0) * 1024 + j * 256 + t] = ph[j];
            stg[(cur * 2 + 1) * 1024 + j * 256 + t] = pl[j];
        }
        if (kc + 1 < KT2) {
            #pragma unroll
            for (int j = 0; j < 4; ++j) {
                ph[j] = b2h8[(size_t)(kc + 1) * 1024 + j * 256 + t];
                pl[j] = b2l8[(size_t)(kc + 1) * 1024 + j * 256 + t];
            }
        }
        __syncthreads();
        const f16x8* lbh = stg + (cur * 2 + 0) * 1024;
        const f16x8* lbl = stg + (cur * 2 + 1) * 1024;
        #pragma unroll
        for (int cs = 0; cs < CS; ++cs) {
            const int ks2 = kc * CS + cs;
            #pragma unroll
            for (int nt2 = 0; nt2 < NT2; ++nt2)
                #pragma unroll
                for (int c = 0; c < 4; ++c) {
                    f16x8 bh = lbh[(cs * NF2 + nt2 * 4 + c) * 64 + l];
                    f16x8 bl = lbl[(cs * NF2 + nt2 * 4 + c) * 64 + l];
                    acc2[nt2][c] = __builtin_amdgcn_mfma_f32_16x16x32_f16(a2h[ks2], bh, acc2[nt2][c], 0, 0, 0);
                    acc2[nt2][c] = __builtin_amdgcn_mfma_f32_16x16x32_f16(a2l[ks2], bh, acc2[nt2][c], 0, 0, 0);
                    acc2[nt2][c] = __builtin_amdgcn_mfma_f32_16x16x32_f16(a2h[ks2], bl, acc2[nt2][c], 0, 0, 0);
                }
        }
        __syncthreads();
    }

    // ---- epilogue: G16 = fp16(dis * acc2), CHUNKED layout [N2/32][M][32] ----
    #pragma unroll
    for (int nt2 = 0; nt2 < NT2; ++nt2)
        #pragma unroll
        for (int r = 0; r < 4; ++r) {
            int m = m0 + lh * 4 + r;
            if (m < M) {
                float sc = dis[m];
                #pragma unroll
                for (int c = 0; c < 4; ++c) {
                    int n = nt2 * 64 + c * 16 + lrow;
                    G16[(size_t)(n >> 5) * ((size_t)M * 32) + (size_t)m * 32 + (n & 31)] =
                        (_Float16)(sc * acc2[nt2][c][r]);
                }
            }
        }
}

// ---------------- Chunked-column aggregation (L2-resident gather) ----------------
// Input g is CHUNKED [C][N][32 cols] fp16 (3.2 MB/chunk -> fits 4 MB per-XCD L2).
// Block = 256 thr = 64 nodes x 4 lanes (one f16x8 oct each). All 782 blocks co-resident;
// in-kernel chunk loop keeps blocks sweeping chunks in near-lockstep.
// MODE 0: oh/ol = split(dis[v]*sum), ROW-MAJOR [N][OPR octs]  (GEMM A-operand)
// MODE 2: o16   = fp16(dis*relu(dis*sum + b)), CHUNKED        (feeds next gather)
// MODE 3: outf  = fp32(dis*sum + b), ROW-MAJOR                (final output)

template <int MODE, int OPR, int C>
__global__ __launch_bounds__(256) void agg_chunk(
    const _Float16* __restrict__ g, const int* __restrict__ row_ptr,
    const int* __restrict__ col, const float* __restrict__ dis,
    const float* __restrict__ bias, float* __restrict__ outf,
    _Float16* __restrict__ o16, _Float16* __restrict__ oh, _Float16* __restrict__ ol) {

    int t = threadIdx.x;
    int nl = t >> 2, c = t & 3;
    int v = blockIdx.x * 64 + nl;
    if (v >= N_NODES) return;

    int s = row_ptr[v], e = row_ptr[v + 1];
    float dv = dis[v];
    const f16x8* gb = (const f16x8*)g;

    #pragma unroll 1
    for (int ch = 0; ch < C; ++ch) {
        const f16x8* g8 = gb + (size_t)ch * (N_NODES * 4);
        f32x8 sum = __builtin_convertvector(g8[(size_t)v * 4 + c], f32x8);  // self-loop
        int i = s;
        for (; i + 4 <= e; i += 4) {
            int u0 = col[i], u1 = col[i + 1], u2 = col[i + 2], u3 = col[i + 3];
            f32x8 f0 = __builtin_convertvector(g8[(size_t)u0 * 4 + c], f32x8);
            f32x8 f1 = __builtin_convertvector(g8[(size_t)u1 * 4 + c], f32x8);
            f32x8 f2 = __builtin_convertvector(g8[(size_t)u2 * 4 + c], f32x8);
            f32x8 f3 = __builtin_convertvector(g8[(size_t)u3 * 4 + c], f32x8);
            sum += (f0 + f1) + (f2 + f3);
        }
        for (; i < e; ++i)
            sum += __builtin_convertvector(g8[(size_t)col[i] * 4 + c], f32x8);

        if (MODE == 0) {
            f16x8 h, lo;
            #pragma unroll
            for (int j = 0; j < 8; ++j) {
                float r = dv * sum[j];
                h[j]  = (_Float16)r;
                lo[j] = (_Float16)(r - (float)h[j]);
            }
            ((f16x8*)oh)[(size_t)v * OPR + ch * 4 + c] = h;
            ((f16x8*)ol)[(size_t)v * OPR + ch * 4 + c] = lo;
        } else if (MODE == 2) {
            f32x8 bv = ((const f32x8*)bias)[ch * 4 + c];
            f16x8 h;
            #pragma unroll
            for (int j = 0; j < 8; ++j) {
                float r = fmaxf(dv * sum[j] + bv[j], 0.f) * dv;
                h[j] = (_Float16)r;
            }
            ((f16x8*)o16)[(size_t)ch * (N_NODES * 4) + (size_t)v * 4 + c] = h;
        } else {
            f32x8 bv = ((const f32x8*)bias)[ch * 4 + c];
            f32x8 r;
            #pragma unroll
            for (int j = 0; j < 8; ++j) r[j] = dv * sum[j] + bv[j];
            ((f32x8*)outf)[(size_t)v * (C * 4) + ch * 4 + c] = r;
        }
    }
}

// ---------------- launch ----------------

extern "C" void kernel_launch(void* const* d_in, const int* in_sizes, int n_in,
                              void* d_out, int out_size, void* d_ws, size_t ws_size,
                              hipStream_t stream) {
    const int N = N_NODES, E = N_EDGES;

    const float* x   = (const float*)d_in[0];
    const int*   ei  = (const int*)d_in[1];
    const int*   src = ei;
    const int*   dst = ei + E;
    const float* W1 = (const float*)d_in[2];  const float* b1 = (const float*)d_in[3];
    const float* W2 = (const float*)d_in[4];  const float* b2 = (const float*)d_in[5];
    const float* W3 = (const float*)d_in[6];  const float* b3 = (const float*)d_in[7];
    const float* W4 = (const float*)d_in[8];  const float* b4 = (const float*)d_in[9];
    float* out = (float*)d_out;

    // workspace carve-up
    char* w = (char*)d_ws;
    int*   counts  = (int*)w;    w += align256((size_t)N * 4);
    int*   row_ptr = (int*)w;    w += align256((size_t)(N + 1) * 4);
    float* dis     = (float*)w;  w += align256((size_t)N * 4);
    int*   bsum    = (int*)w;    w += align256((size_t)64 * 4);
    int*   rank    = (int*)w;    w += align256((size_t)E * 4);
    int*   col     = (int*)w;    w += align256((size_t)E * 4);
    _Float16* w1h = (_Float16*)w; w += align256(32768 * 2);
    _Float16* w1l = (_Float16*)w; w += align256(32768 * 2);
    _Float16* w2h = (_Float16*)w; w += align256(16384 * 2);
    _Float16* w2l = (_Float16*)w; w += align256(16384 * 2);
    _Float16* w3h = (_Float16*)w; w += align256(16384 * 2);
    _Float16* w3l = (_Float16*)w; w += align256(16384 * 2);
    _Float16* w4h = (_Float16*)w; w += align256(32768 * 2);
    _Float16* w4l = (_Float16*)w; w += align256(32768 * 2);
    _Float16* xs  = (_Float16*)w; w += align256((size_t)N * 128 * 2);   // chunked [4][N][32]
    _Float16* t1h = (_Float16*)w; w += align256((size_t)N * 128 * 2);   // row-major [N][128]
    _Float16* t1l = (_Float16*)w; w += align256((size_t)N * 128 * 2);
    _Float16* g2  = (_Float16*)w; w += align256((size_t)N * 64 * 2);    // chunked [2][N][32]
    _Float16* h2s = (_Float16*)w; w += align256((size_t)N * 64 * 2);    // chunked [2][N][32]
    _Float16* t3h = (_Float16*)w; w += align256((size_t)N * 64 * 2);    // row-major [N][64]
    _Float16* t3l = (_Float16*)w; w += align256((size_t)N * 64 * 2);
    _Float16* gg4 = (_Float16*)w; w += align256((size_t)N * 128 * 2);   // chunked [4][N][32]

    // ---- CSR build ----
    const int nb = (N + 1023) / 1024;
    hipMemsetAsync(counts, 0, (size_t)N * 4, stream);
    count_kernel<<<(E + 255) / 256, 256, 0, stream>>>(dst, counts, rank, E);
    scan1_kernel<<<nb, 1024, 0, stream>>>(counts, row_ptr, bsum, N);
    scan3_kernel<<<(N + 255) / 256, 256, 0, stream>>>(row_ptr, bsum, counts, dis, N);
    fill_kernel<<<(E + 255) / 256, 256, 0, stream>>>(src, dst, rank, row_ptr, col, E);

    // ---- fused prep: 4x pack_w + xs (chunked) ----
    prep_kernel<<<48 + (N * 16 + 255) / 256, 256, 0, stream>>>(
        W1, w1h, w1l, W2, w2h, w2l, W3, w3h, w3l, W4, w4h, w4l, x, dis, xs);

    const int ga = (N + 63) / 64;   // 782 blocks (64 nodes each)
    const int gx = (N + 63) / 64;   // 782 blocks for fused_gemm

    // ---- L1+L2: t1 = As xs (chunked gather) ; g2 = dis*(relu(t1 @ W1 + b1) @ W2) ----
    agg_chunk<0, 16, 4><<<ga, 256, 0, stream>>>(xs, row_ptr, col, dis, nullptr,
                                                nullptr, nullptr, t1h, t1l);
    fused_gemm<128, 64><<<gx, 256, 0, stream>>>(t1h, t1l, dis, b1,
                                                w1h, w1l, w2h, w2l, g2, N);
    // ---- agg 2: h2s = fp16(dis * relu(dis*(sum g2) + b2)) (chunked in+out) ----
    agg_chunk<2, 0, 2><<<ga, 256, 0, stream>>>(g2, row_ptr, col, dis, b2,
                                               nullptr, h2s, nullptr, nullptr);

    // ---- L3+L4: t3 = As h2s (chunked gather) ; gg4 = dis*(relu(t3 @ W3 + b3) @ W4) ----
    agg_chunk<0, 8, 2><<<ga, 256, 0, stream>>>(h2s, row_ptr, col, dis, nullptr,
                                               nullptr, nullptr, t3h, t3l);
    fused_gemm<64, 128><<<gx, 256, 0, stream>>>(t3h, t3l, dis, b3,
                                                w3h, w3l, w4h, w4l, gg4, N);
    // ---- agg 4: out = dis*(sum gg4) + b4 (chunked in, row-major fp32 out) ----
    agg_chunk<3, 0, 4><<<ga, 256, 0, stream>>>(gg4, row_ptr, col, dis, b4,
                                               out, nullptr, nullptr, nullptr);
}

// Round 13
// 217.945 us; speedup vs baseline: 1.1626x; 1.1626x over previous
//
#include <hip/hip_runtime.h>

#define N_NODES 50000
#define N_EDGES 800000

static inline size_t align256(size_t x) { return (x + 255) & ~(size_t)255; }

typedef _Float16 f16x8 __attribute__((ext_vector_type(8)));   // 8 fp16 in 4 VGPRs
typedef float f32x4 __attribute__((ext_vector_type(4)));
typedef float f32x8 __attribute__((ext_vector_type(8)));

// ---------------- CSR build ----------------

__global__ void count_kernel(const int* __restrict__ dst, int* __restrict__ counts,
                             int* __restrict__ rank, int E) {
    int e = blockIdx.x * blockDim.x + threadIdx.x;
    if (e < E) rank[e] = atomicAdd(&counts[dst[e]], 1);
}

__global__ void scan1_kernel(const int* __restrict__ counts, int* __restrict__ row_ptr,
                             int* __restrict__ bsum, int n) {
    __shared__ int sd[1024];
    int i = blockIdx.x * 1024 + threadIdx.x;
    int v = (i < n) ? counts[i] : 0;
    sd[threadIdx.x] = v;
    __syncthreads();
    #pragma unroll
    for (int off = 1; off < 1024; off <<= 1) {
        int t = 0;
        if ((int)threadIdx.x >= off) t = sd[threadIdx.x - off];
        __syncthreads();
        sd[threadIdx.x] += t;
        __syncthreads();
    }
    if (i < n) row_ptr[i + 1] = sd[threadIdx.x];
    if (threadIdx.x == 1023) bsum[blockIdx.x] = sd[1023];
}

// finalize scan (local sum over <=48 block sums), plus dis.
__global__ void scan3_kernel(int* __restrict__ row_ptr, const int* __restrict__ bsum,
                             const int* __restrict__ counts, float* __restrict__ dis, int n) {
    __shared__ int pfx_s;
    if (threadIdx.x == 0) {
        int nb = blockIdx.x >> 2;        // 1024/256
        int p = 0;
        for (int j = 0; j < nb; ++j) p += bsum[j];
        pfx_s = p;
    }
    __syncthreads();
    int i = blockIdx.x * blockDim.x + threadIdx.x;
    if (i < n) {
        row_ptr[i + 1] += pfx_s;
        dis[i] = rsqrtf((float)(counts[i] + 1));
        if (i == 0) row_ptr[0] = 0;
    }
}

__global__ void fill_kernel(const int* __restrict__ src, const int* __restrict__ dst,
                            const int* __restrict__ rank, const int* __restrict__ row_ptr,
                            int* __restrict__ col, int E) {
    int e = blockIdx.x * blockDim.x + threadIdx.x;
    if (e < E) col[row_ptr[dst[e]] + rank[e]] = src[e];
}

// ---------------- fused prep: pack 4 weights (hi/lo frag order) + xs = fp16(dis*x) ----

__device__ __forceinline__ void pack_dev(const float* __restrict__ W,
                                         _Float16* __restrict__ Ph, _Float16* __restrict__ Pl,
                                         int K, int N, int id) {
    int l = id & 63;
    int f = id >> 6;
    int nf16 = N >> 4;
    int ks = f / nf16, nf = f - ks * nf16;
    int k0 = ks * 32 + (l >> 4) * 8;
    int n  = nf * 16 + (l & 15);
    #pragma unroll
    for (int j = 0; j < 8; ++j) {
        float v = W[(size_t)(k0 + j) * N + n];
        _Float16 hi = (_Float16)v;
        Ph[(size_t)id * 8 + j] = hi;
        Pl[(size_t)id * 8 + j] = (_Float16)(v - (float)hi);
    }
}

__global__ void prep_kernel(const float* __restrict__ W1, _Float16* __restrict__ w1h, _Float16* __restrict__ w1l,
                            const float* __restrict__ W2, _Float16* __restrict__ w2h, _Float16* __restrict__ w2l,
                            const float* __restrict__ W3, _Float16* __restrict__ w3h, _Float16* __restrict__ w3l,
                            const float* __restrict__ W4, _Float16* __restrict__ w4h, _Float16* __restrict__ w4l,
                            const float* __restrict__ x, const float* __restrict__ dis,
                            _Float16* __restrict__ xs) {
    int b = blockIdx.x;
    int tid = threadIdx.x;
    if (b < 16) {                       // W1: 4096 ids
        pack_dev(W1, w1h, w1l, 128, 256, b * 256 + tid);
    } else if (b < 24) {                // W2: 2048 ids
        pack_dev(W2, w2h, w2l, 256, 64, (b - 16) * 256 + tid);
    } else if (b < 32) {                // W3: 2048 ids
        pack_dev(W3, w3h, w3l, 64, 256, (b - 24) * 256 + tid);
    } else if (b < 48) {                // W4: 4096 ids
        pack_dev(W4, w4h, w4l, 256, 128, (b - 32) * 256 + tid);
    } else {                            // xs: N*16 octs of 8, row-major
        int q = (b - 48) * 256 + tid;
        if (q < N_NODES * 16) {
            int v = q >> 4, o = q & 15;
            float s = dis[v];
            const float* px = x + (size_t)v * 128 + o * 8;
            float4 t0 = *(const float4*)px;
            float4 t1 = *(const float4*)(px + 4);
            f16x8 h;
            h[0] = (_Float16)(s * t0.x); h[1] = (_Float16)(s * t0.y);
            h[2] = (_Float16)(s * t0.z); h[3] = (_Float16)(s * t0.w);
            h[4] = (_Float16)(s * t1.x); h[5] = (_Float16)(s * t1.y);
            h[6] = (_Float16)(s * t1.z); h[7] = (_Float16)(s * t1.w);
            ((f16x8*)xs)[q] = h;
        }
    }
}

// ---------------- Fused GEMM1+GEMM2 (fp16 split x3), NO gather ----------------
// Block = 256 thr = 4 waves; wave = 16 rows (one m-frag); block = 64 rows.
// Phase B: h = relu(A @ W1 + b1), A hi/lo frags from GLOBAL (row-local), W1 LDS-dbuf.
//          Single barrier per k-slice (2-buffer proof: a wave reaching writes of
//          slice k+2 passed barrier k+1, which orders all MFMA reads of slice k).
// Phase C: h fp32 -> per-wave LDS transpose (stride 17 words).
// Phase D: A2 frags (hi/lo) from transpose.
// Phase E: G16 = fp16(dis * (h @ W2)), W2 LDS-dbuf, single barrier per chunk.
// LDS: union { B-stage [2][2][1024] octs (64KB) ; xpose 4 x 4352 f32 (68KB) } = 69632 B.

template <int K1, int N2>
__global__ __launch_bounds__(256) void fused_gemm(
    const _Float16* __restrict__ Ah, const _Float16* __restrict__ Al,
    const float* __restrict__ dis, const float* __restrict__ bias1,
    const _Float16* __restrict__ B1h, const _Float16* __restrict__ B1l,
    const _Float16* __restrict__ B2h, const _Float16* __restrict__ B2l,
    _Float16* __restrict__ G16, int M) {

    constexpr int KS  = K1 / 32;    // GEMM1 k-slices (= A1 frag count)
    constexpr int NF2 = N2 / 16;
    constexpr int NT2 = N2 / 64;
    constexpr int CS  = 16 / NF2;   // slices per B2 chunk (chunk = 1024 octs per h/l)
    constexpr int KT2 = 8 / CS;     // B2 chunks

    __shared__ __align__(16) char ldsb[69632];
    f16x8* stg = (f16x8*)ldsb;      // [buf][hi/lo][1024]

    const int t = threadIdx.x, w = t >> 6, l = t & 63;
    const int lrow = l & 15, lh = l >> 4;
    const int m0 = blockIdx.x * 64 + w * 16;
    const int v = m0 + lrow;
    const bool okv = v < M;

    // ---- A1 frags from global (hi/lo already split) ----
    f16x8 z8 = {0, 0, 0, 0, 0, 0, 0, 0};
    const f16x8* pAh = (const f16x8*)(Ah + (size_t)v * K1);
    const f16x8* pAl = (const f16x8*)(Al + (size_t)v * K1);
    f16x8 pah[KS], pal[KS];
    #pragma unroll
    for (int ks = 0; ks < KS; ++ks) {
        pah[ks] = okv ? pAh[ks * 4 + lh] : z8;
        pal[ks] = okv ? pAl[ks * 4 + lh] : z8;
    }

    // ---- phase B: GEMM1 (N1 = 256, 16 frags per slice), LDS-dbuf, 1 barrier/slice ----
    const f16x8* b1h8 = (const f16x8*)B1h;
    const f16x8* b1l8 = (const f16x8*)B1l;
    f16x8 ph[4], pl[4];
    #pragma unroll
    for (int j = 0; j < 4; ++j) { ph[j] = b1h8[j * 256 + t]; pl[j] = b1l8[j * 256 + t]; }

    f32x4 acc1[4][4] = {};
    #pragma unroll
    for (int ks = 0; ks < KS; ++ks) {
        const int cur = ks & 1;
        #pragma unroll
        for (int j = 0; j < 4; ++j) {
            stg[(cur * 2 + 0) * 1024 + j * 256 + t] = ph[j];
            stg[(cur * 2 + 1) * 1024 + j * 256 + t] = pl[j];
        }
        if (ks + 1 < KS) {
            #pragma unroll
            for (int j = 0; j < 4; ++j) {
                ph[j] = b1h8[(size_t)(ks + 1) * 1024 + j * 256 + t];
                pl[j] = b1l8[(size_t)(ks + 1) * 1024 + j * 256 + t];
            }
        }
        __syncthreads();
        const f16x8* lbh = stg + (cur * 2 + 0) * 1024;
        const f16x8* lbl = stg + (cur * 2 + 1) * 1024;
        #pragma unroll
        for (int nt = 0; nt < 4; ++nt)
            #pragma unroll
            for (int c = 0; c < 4; ++c) {
                f16x8 bh = lbh[(nt * 4 + c) * 64 + l];
                f16x8 bl = lbl[(nt * 4 + c) * 64 + l];
                acc1[nt][c] = __builtin_amdgcn_mfma_f32_16x16x32_f16(pah[ks], bh, acc1[nt][c], 0, 0, 0);
                acc1[nt][c] = __builtin_amdgcn_mfma_f32_16x16x32_f16(pal[ks], bh, acc1[nt][c], 0, 0, 0);
                acc1[nt][c] = __builtin_amdgcn_mfma_f32_16x16x32_f16(pah[ks], bl, acc1[nt][c], 0, 0, 0);
            }
    }
    __syncthreads();                 // all B1 reads done before xpose overwrites stage

    // ---- phase C: h = relu(acc1 + b1) -> per-wave LDS transpose ----
    float* xp = (float*)ldsb + (size_t)w * 4352;   // [col 0..255][row 0..15], stride 17
    #pragma unroll
    for (int nt = 0; nt < 4; ++nt)
        #pragma unroll
        for (int c = 0; c < 4; ++c) {
            float bb = bias1[nt * 64 + c * 16 + lrow];
            #pragma unroll
            for (int r = 0; r < 4; ++r) {
                float hv = fmaxf(acc1[nt][c][r] + bb, 0.f);
                xp[(nt * 64 + c * 16 + lrow) * 17 + lh * 4 + r] = hv;
            }
        }

    // prefetch B2 chunk 0 into regs (global latency overlaps phase D LDS reads)
    const f16x8* b2h8 = (const f16x8*)B2h;
    const f16x8* b2l8 = (const f16x8*)B2l;
    #pragma unroll
    for (int j = 0; j < 4; ++j) { ph[j] = b2h8[j * 256 + t]; pl[j] = b2l8[j * 256 + t]; }

    // ---- phase D: A2 frags from transpose (row = lrow, k = lh*8 + j + 32*ks2) ----
    f16x8 a2h[8], a2l[8];
    #pragma unroll
    for (int ks2 = 0; ks2 < 8; ++ks2)
        #pragma unroll
        for (int j = 0; j < 8; ++j) {
            float vv = xp[(ks2 * 32 + lh * 8 + j) * 17 + lrow];
            a2h[ks2][j] = (_Float16)vv;
            a2l[ks2][j] = (_Float16)(vv - (float)a2h[ks2][j]);
        }
    __syncthreads();                 // all xpose reads done before B2 staging

    // ---- phase E: GEMM2 (K2 = 256 = 8 slices, chunks of CS slices), 1 barrier/chunk ----
    f32x4 acc2[NT2][4] = {};
    #pragma unroll
    for (int kc = 0; kc < KT2; ++kc) {
        const int cur = kc & 1;
        #pragma unroll
        for (int j = 0; j < 4; ++j) {
            stg[(cur * 2 + 0) * 1024 + j * 256 + t] = ph[j];
            stg[(cur * 2 + 1) * 1024 + j * 256 + t] = pl[j];
        }
        if (kc + 1 < KT2) {
            #pragma unroll
            for (int j = 0; j < 4; ++j) {
                ph[j] = b2h8[(size_t)(kc + 1) * 1024 + j * 256 + t];
                pl[j] = b2l8[(size_t)(kc + 1) * 1024 + j * 256 + t];
            }
        }
        __syncthreads();
        const f16x8* lbh = stg + (cur * 2 + 0) * 1024;
        const f16x8* lbl = stg + (cur * 2 + 1) * 1024;
        #pragma unroll
        for (int cs = 0; cs < CS; ++cs) {
            const int ks2 = kc * CS + cs;
            #pragma unroll
            for (int nt2 = 0; nt2 < NT2; ++nt2)
                #pragma unroll
                for (int c = 0; c < 4; ++c) {
                    f16x8 bh = lbh[(cs * NF2 + nt2 * 4 + c) * 64 + l];
                    f16x8 bl = lbl[(cs * NF2 + nt2 * 4 + c) * 64 + l];
                    acc2[nt2][c] = __builtin_amdgcn_mfma_f32_16x16x32_f16(a2h[ks2], bh, acc2[nt2][c], 0, 0, 0);
                    acc2[nt2][c] = __builtin_amdgcn_mfma_f32_16x16x32_f16(a2l[ks2], bh, acc2[nt2][c], 0, 0, 0);
                    acc2[nt2][c] = __builtin_amdgcn_mfma_f32_16x16x32_f16(a2h[ks2], bl, acc2[nt2][c], 0, 0, 0);
                }
        }
    }

    // ---- epilogue: G16 = fp16(dis * acc2), row-major ----
    #pragma unroll
    for (int nt2 = 0; nt2 < NT2; ++nt2)
        #pragma unroll
        for (int r = 0; r < 4; ++r) {
            int m = m0 + lh * 4 + r;
            if (m < M) {
                float sc = dis[m];
                #pragma unroll
                for (int c = 0; c < 4; ++c)
                    G16[(size_t)m * N2 + nt2 * 64 + c * 16 + lrow] = (_Float16)(sc * acc2[nt2][c][r]);
            }
        }
}

// ---------------- Aggregation (fp16 gather, LDS-staged col, serial per node) ----------
// DQ8 = D/8 lanes per node; block = 256 threads = NPB nodes.
// The block's CSR col range is contiguous -> cooperatively stage into LDS once
// (coalesced), then the gather loop reads col from LDS broadcast (frees ~half of
// all VMEM instruction issue). Global fallback if block edges > CAP.
// MODE 0: out split(dis[v]*sum) -> oh/ol     MODE 2: out fp16(dis*relu(dis*sum+b)) -> o16
// MODE 3: out fp32(dis*sum + b) -> outf

template <int MODE, int DQ8>
__global__ __launch_bounds__(256) void agg8(
    const _Float16* __restrict__ g, const int* __restrict__ row_ptr,
    const int* __restrict__ col, const float* __restrict__ dis,
    const float* __restrict__ bias, float* __restrict__ outf,
    _Float16* __restrict__ o16, _Float16* __restrict__ oh, _Float16* __restrict__ ol) {
    constexpr int NPB = 256 / DQ8;
    constexpr int CAP = NPB * 64;        // 4x mean degree headroom
    __shared__ int lcol[CAP];
    __shared__ int sb2[2];

    int t = threadIdx.x;
    int v0 = blockIdx.x * NPB;
    int vend = v0 + NPB; if (vend > N_NODES) vend = N_NODES;
    if (t == 0) { sb2[0] = row_ptr[v0]; sb2[1] = row_ptr[vend]; }
    __syncthreads();
    const int base = sb2[0];
    const int tot  = sb2[1] - base;
    const bool use_lds = (tot <= CAP);
    if (use_lds) {
        for (int j = t; j < tot; j += 256) lcol[j] = col[base + j];
    }
    __syncthreads();

    int nl = t / DQ8, c = t % DQ8;
    int v = v0 + nl;
    if (v >= N_NODES) return;
    const f16x8* g8 = (const f16x8*)g;
    size_t rowo = (size_t)v * DQ8 + c;

    f32x8 sum = __builtin_convertvector(g8[rowo], f32x8);   // self-loop term
    int s = row_ptr[v], e = row_ptr[v + 1];

    if (use_lds) {
        int i = s - base, en = e - base;
        for (; i + 4 <= en; i += 4) {
            int u0 = lcol[i], u1 = lcol[i + 1], u2 = lcol[i + 2], u3 = lcol[i + 3];
            f32x8 f0 = __builtin_convertvector(g8[(size_t)u0 * DQ8 + c], f32x8);
            f32x8 f1 = __builtin_convertvector(g8[(size_t)u1 * DQ8 + c], f32x8);
            f32x8 f2 = __builtin_convertvector(g8[(size_t)u2 * DQ8 + c], f32x8);
            f32x8 f3 = __builtin_convertvector(g8[(size_t)u3 * DQ8 + c], f32x8);
            sum += (f0 + f1) + (f2 + f3);
        }
        for (; i < en; ++i)
            sum += __builtin_convertvector(g8[(size_t)lcol[i] * DQ8 + c], f32x8);
    } else {
        int i = s;
        for (; i + 4 <= e; i += 4) {
            int u0 = col[i], u1 = col[i + 1], u2 = col[i + 2], u3 = col[i + 3];
            f32x8 f0 = __builtin_convertvector(g8[(size_t)u0 * DQ8 + c], f32x8);
            f32x8 f1 = __builtin_convertvector(g8[(size_t)u1 * DQ8 + c], f32x8);
            f32x8 f2 = __builtin_convertvector(g8[(size_t)u2 * DQ8 + c], f32x8);
            f32x8 f3 = __builtin_convertvector(g8[(size_t)u3 * DQ8 + c], f32x8);
            sum += (f0 + f1) + (f2 + f3);
        }
        for (; i < e; ++i)
            sum += __builtin_convertvector(g8[(size_t)col[i] * DQ8 + c], f32x8);
    }

    float dv = dis[v];
    if (MODE == 0) {
        f16x8 h, lo;
        #pragma unroll
        for (int j = 0; j < 8; ++j) {
            float r = dv * sum[j];
            h[j]  = (_Float16)r;
            lo[j] = (_Float16)(r - (float)h[j]);
        }
        ((f16x8*)oh)[rowo] = h;
        ((f16x8*)ol)[rowo] = lo;
    } else if (MODE == 2) {
        f32x8 bv = ((const f32x8*)bias)[c];
        f16x8 h;
        #pragma unroll
        for (int j = 0; j < 8; ++j) {
            float r = fmaxf(dv * sum[j] + bv[j], 0.f) * dv;
            h[j] = (_Float16)r;
        }
        ((f16x8*)o16)[rowo] = h;
    } else {
        f32x8 bv = ((const f32x8*)bias)[c];
        f32x8 r;
        #pragma unroll
        for (int j = 0; j < 8; ++j) r[j] = dv * sum[j] + bv[j];
        ((f32x8*)outf)[rowo] = r;
    }
}

// ---------------- launch ----------------

extern "C" void kernel_launch(void* const* d_in, const int* in_sizes, int n_in,
                              void* d_out, int out_size, void* d_ws, size_t ws_size,
                              hipStream_t stream) {
    const int N = N_NODES, E = N_EDGES;

    const float* x   = (const float*)d_in[0];
    const int*   ei  = (const int*)d_in[1];
    const int*   src = ei;
    const int*   dst = ei + E;
    const float* W1 = (const float*)d_in[2];  const float* b1 = (const float*)d_in[3];
    const float* W2 = (const float*)d_in[4];  const float* b2 = (const float*)d_in[5];
    const float* W3 = (const float*)d_in[6];  const float* b3 = (const float*)d_in[7];
    const float* W4 = (const float*)d_in[8];  const float* b4 = (const float*)d_in[9];
    float* out = (float*)d_out;

    // workspace carve-up
    char* w = (char*)d_ws;
    int*   counts  = (int*)w;    w += align256((size_t)N * 4);
    int*   row_ptr = (int*)w;    w += align256((size_t)(N + 1) * 4);
    float* dis     = (float*)w;  w += align256((size_t)N * 4);
    int*   bsum    = (int*)w;    w += align256((size_t)64 * 4);
    int*   rank    = (int*)w;    w += align256((size_t)E * 4);
    int*   col     = (int*)w;    w += align256((size_t)E * 4);
    _Float16* w1h = (_Float16*)w; w += align256(32768 * 2);
    _Float16* w1l = (_Float16*)w; w += align256(32768 * 2);
    _Float16* w2h = (_Float16*)w; w += align256(16384 * 2);
    _Float16* w2l = (_Float16*)w; w += align256(16384 * 2);
    _Float16* w3h = (_Float16*)w; w += align256(16384 * 2);
    _Float16* w3l = (_Float16*)w; w += align256(16384 * 2);
    _Float16* w4h = (_Float16*)w; w += align256(32768 * 2);
    _Float16* w4l = (_Float16*)w; w += align256(32768 * 2);
    _Float16* xs  = (_Float16*)w; w += align256((size_t)N * 128 * 2);
    _Float16* t1h = (_Float16*)w; w += align256((size_t)N * 128 * 2);
    _Float16* t1l = (_Float16*)w; w += align256((size_t)N * 128 * 2);
    _Float16* g2  = (_Float16*)w; w += align256((size_t)N * 64 * 2);
    _Float16* h2s = (_Float16*)w; w += align256((size_t)N * 64 * 2);
    _Float16* t3h = (_Float16*)w; w += align256((size_t)N * 64 * 2);
    _Float16* t3l = (_Float16*)w; w += align256((size_t)N * 64 * 2);
    _Float16* gg4 = (_Float16*)w; w += align256((size_t)N * 128 * 2);

    // ---- CSR build ----
    const int nb = (N + 1023) / 1024;
    hipMemsetAsync(counts, 0, (size_t)N * 4, stream);
    count_kernel<<<(E + 255) / 256, 256, 0, stream>>>(dst, counts, rank, E);
    scan1_kernel<<<nb, 1024, 0, stream>>>(counts, row_ptr, bsum, N);
    scan3_kernel<<<(N + 255) / 256, 256, 0, stream>>>(row_ptr, bsum, counts, dis, N);
    fill_kernel<<<(E + 255) / 256, 256, 0, stream>>>(src, dst, rank, row_ptr, col, E);

    // ---- fused prep: 4x pack_w + xs ----
    prep_kernel<<<48 + (N * 16 + 255) / 256, 256, 0, stream>>>(
        W1, w1h, w1l, W2, w2h, w2l, W3, w3h, w3l, W4, w4h, w4l, x, dis, xs);

    const int gx = (N + 63) / 64;   // 782 blocks for fused_gemm

    // ---- L1+L2: t1 = As xs (gather) ; g2 = dis * (relu(t1 @ W1 + b1) @ W2) (fused) ----
    agg8<0, 16><<<(N + 15) / 16, 256, 0, stream>>>(xs, row_ptr, col, dis, nullptr,
                                                   nullptr, nullptr, t1h, t1l);
    fused_gemm<128, 64><<<gx, 256, 0, stream>>>(t1h, t1l, dis, b1,
                                                w1h, w1l, w2h, w2l, g2, N);
    // ---- agg 2: h2s = fp16(dis * relu(dis*(sum g2) + b2)) ----
    agg8<2, 8><<<(N + 31) / 32, 256, 0, stream>>>(g2, row_ptr, col, dis, b2,
                                                  nullptr, h2s, nullptr, nullptr);

    // ---- L3+L4: t3 = As h2s (gather) ; gg4 = dis * (relu(t3 @ W3 + b3) @ W4) (fused) ----
    agg8<0, 8><<<(N + 31) / 32, 256, 0, stream>>>(h2s, row_ptr, col, dis, nullptr,
                                                  nullptr, nullptr, t3h, t3l);
    fused_gemm<64, 128><<<gx, 256, 0, stream>>>(t3h, t3l, dis, b3,
                                                w3h, w3l, w4h, w4l, gg4, N);
    // ---- agg 4: out = dis*(sum gg4) + b4 ----
    agg8<3, 16><<<(N + 15) / 16, 256, 0, stream>>>(gg4, row_ptr, col, dis, b4,
                                                   out, nullptr, nullptr, nullptr);
}